// Round 3
// baseline (373.494 us; speedup 1.0000x reference)
//
#include <hip/hip_runtime.h>

// ShiftedWindowAttention3d on MI355X (gfx950).
// x[1,16,56,56,192], WIN=(8,7,7), SHIFT=(4,3,3) -> no pad, shifted.
// 128 windows x 392 tokens, 6 heads x hd=32.
// Round 3: round-2 design with fixed builtins (mfma_f32_16x16x16f16, amdgcn_exp2f).
// Swapped-S attention (P frag feeds 16x16x16 PV directly, no transpose),
// f16 bias+mask tables pre-scaled by log2e, exp2 softmax, 3 blocks/CU.

typedef _Float16 f16;
typedef __attribute__((ext_vector_type(8))) _Float16 f16x8;
typedef __attribute__((ext_vector_type(4))) _Float16 f16x4;
typedef __attribute__((ext_vector_type(4))) float f32x4;

#define MFMA_K32(a, b, c) __builtin_amdgcn_mfma_f32_16x16x32_f16((a), (b), (c), 0, 0, 0)
#define MFMA_K16(a, b, c) __builtin_amdgcn_mfma_f32_16x16x16f16((a), (b), (c), 0, 0, 0)
#define EXP2F(x) __builtin_amdgcn_exp2f(x)

#define HEADS 6
#define NWIN 128
#define NTOK 392
#define CDIM 192
#define LOG2E 1.4426950408889634f
#define QSCALE 0.2550868562622215f   // hd^-0.5 * log2e

__device__ inline f16x8 f16x8_zero() {
    f16x8 v = {(f16)0.f,(f16)0.f,(f16)0.f,(f16)0.f,(f16)0.f,(f16)0.f,(f16)0.f,(f16)0.f};
    return v;
}

// ---------------- kernel 0a: weights fp32 -> f16 (q rows pre-scaled) ----------------
__global__ __launch_bounds__(256) void wconv_kernel(
    const float* __restrict__ wqkv, const float* __restrict__ wproj,
    f16* __restrict__ wqkv_h, f16* __restrict__ wproj_h)
{
    int i = blockIdx.x * 256 + threadIdx.x;
    if (i < 576 * 192) {
        float s = (i < 192 * 192) ? QSCALE : 1.0f;
        wqkv_h[i] = (f16)(wqkv[i] * s);
    }
    if (i < 192 * 192) wproj_h[i] = (f16)wproj[i];
}

// ---------------- kernel 0b: f16 bias tables (pre-scaled by log2e) ----------------
// rpb_h[6][400][400]: rel-pos bias * log2e; -60000 in 392..399 pad rows/cols.
// mask_h[8][400][400]: shift mask * log2e (0 or -144.27); 0 in pad (avoid -inf sums).
__global__ __launch_bounds__(256) void tab_kernel(
    const float* __restrict__ tbl, f16* __restrict__ rpb_h, f16* __restrict__ mask_h)
{
    int i = blockIdx.x * 256 + threadIdx.x;
    if (i < 6 * 160000) {
        int h = i / 160000, r = i - h * 160000, n = r / 400, m = r - n * 400;
        float v;
        if (n < NTOK && m < NTOK) {
            int td = n / 49, t2 = n - td * 49, th = t2 / 7, tw = t2 - th * 7;
            int md = m / 49, m2 = m - md * 49, mh = m2 / 7, mw = m2 - mh * 7;
            int idx = ((td - md + 7) * 13 + (th - mh + 6)) * 13 + (tw - mw + 6);
            v = tbl[idx * 6 + h] * LOG2E;
        } else {
            v = -60000.0f;
        }
        rpb_h[i] = (f16)v;
    }
    if (i < 8 * 160000) {
        int wt = i / 160000, r = i - wt * 160000, n = r / 400, m = r - n * 400;
        float v = 0.0f;
        if (n < NTOK && m < NTOK) {
            int td = n / 49, t2 = n - td * 49, th = t2 / 7, tw = t2 - th * 7;
            int md = m / 49, m2 = m - md * 49, mh = m2 / 7, mw = m2 - mh * 7;
            int rn = ((wt & 4) ? (td < 4 ? 1 : 2) : 0) * 9 +
                     ((wt & 2) ? (th < 4 ? 1 : 2) : 0) * 3 +
                     ((wt & 1) ? (tw < 4 ? 1 : 2) : 0);
            int rm = ((wt & 4) ? (md < 4 ? 1 : 2) : 0) * 9 +
                     ((wt & 2) ? (mh < 4 ? 1 : 2) : 0) * 3 +
                     ((wt & 1) ? (mw < 4 ? 1 : 2) : 0);
            v = (rn == rm) ? 0.0f : (-100.0f * LOG2E);
        }
        mask_h[i] = (f16)v;
    }
}

// ---------------- kernel 1: gather(roll+window) + QKV GEMM ----------------
// grid 784: 64-token tile x all 576 outputs (two 288-halves). 256 threads.
__global__ __launch_bounds__(256, 3) void qkv_kernel(
    const float* __restrict__ x, const f16* __restrict__ wq,
    const float* __restrict__ bq,
    f16* __restrict__ q_ws, f16* __restrict__ k_ws, f16* __restrict__ v_ws)
{
    __shared__ __align__(16) f16 a_lds[64 * 256];  // 32 KB, swizzled
    const int tid = threadIdx.x;
    const int bm = blockIdx.x * 64;

    for (int i = tid; i < 64 * 24; i += 256) {
        int row = i / 24, c = i - row * 24;
        int tok = bm + row;
        int win = tok / NTOK, nloc = tok - win * NTOK;
        int td = nloc / 49, r2 = nloc - td * 49, th = r2 / 7, tw = r2 - th * 7;
        int wd = win >> 6, wh = (win >> 3) & 7, ww = win & 7;
        int d = (wd * 8 + td + 4) & 15;
        int hh = wh * 7 + th + 3; if (hh >= 56) hh -= 56;
        int wco = ww * 7 + tw + 3; if (wco >= 56) wco -= 56;
        const float* src = x + ((d * 56 + hh) * 56 + wco) * CDIM + c * 8;
        const float4 u0 = *(const float4*)(src);
        const float4 u1 = *(const float4*)(src + 4);
        f16x8 v;
        v[0] = (f16)u0.x; v[1] = (f16)u0.y; v[2] = (f16)u0.z; v[3] = (f16)u0.w;
        v[4] = (f16)u1.x; v[5] = (f16)u1.y; v[6] = (f16)u1.z; v[7] = (f16)u1.w;
        *(f16x8*)&a_lds[row * 256 + ((c ^ (row & 7)) << 3)] = v;
    }
    __syncthreads();

    const int lane = tid & 63, wv = tid >> 6;
    const int l15 = lane & 15, g = lane >> 4;
    const int m0 = (wv & 1) * 32, nq = wv >> 1;
    const f32x4 z4 = {0.f, 0.f, 0.f, 0.f};

    for (int half = 0; half < 2; half++) {
        const int n0 = half * 288 + nq * 144;
        f32x4 acc[2][9];
        #pragma unroll
        for (int mi = 0; mi < 2; mi++)
            #pragma unroll
            for (int ni = 0; ni < 9; ni++) acc[mi][ni] = z4;

        #pragma unroll
        for (int kk = 0; kk < 6; kk++) {
            f16x8 af[2];
            #pragma unroll
            for (int mi = 0; mi < 2; mi++) {
                int row = m0 + mi * 16 + l15;
                af[mi] = *(const f16x8*)&a_lds[row * 256 + (((kk * 4 + g) ^ (row & 7)) << 3)];
            }
            #pragma unroll
            for (int ni = 0; ni < 9; ni++) {
                const f16x8 bf = *(const f16x8*)&wq[(n0 + ni * 16 + l15) * CDIM + kk * 32 + g * 8];
                #pragma unroll
                for (int mi = 0; mi < 2; mi++)
                    acc[mi][ni] = MFMA_K32(af[mi], bf, acc[mi][ni]);
            }
        }

        #pragma unroll
        for (int mi = 0; mi < 2; mi++) {
            const int tok0 = bm + m0 + mi * 16 + g * 4;
            const int win = tok0 / NTOK, nloc0 = tok0 - win * NTOK;
            #pragma unroll
            for (int ni = 0; ni < 9; ni++) {
                const int n = n0 + ni * 16 + l15;
                const float bias = bq[n] * ((n < 192) ? QSCALE : 1.0f);
                if (n < 192) {
                    const int head = n >> 5, hd = n & 31;
                    f16* dst = q_ws + ((win * HEADS + head) * NTOK + nloc0) * 32 + hd;
                    #pragma unroll
                    for (int j = 0; j < 4; j++)
                        dst[j * 32] = (f16)(acc[mi][ni][j] + bias);
                } else if (n < 384) {
                    const int cc = n - 192, head = cc >> 5, hd = cc & 31;
                    f16* dst = k_ws + ((win * HEADS + head) * NTOK + nloc0) * 32 + hd;
                    #pragma unroll
                    for (int j = 0; j < 4; j++)
                        dst[j * 32] = (f16)(acc[mi][ni][j] + bias);
                } else {
                    const int cc = n - 384, head = cc >> 5, hd = cc & 31;
                    f16x4 pk;
                    #pragma unroll
                    for (int j = 0; j < 4; j++) pk[j] = (f16)(acc[mi][ni][j] + bias);
                    *(f16x4*)(v_ws + ((win * HEADS + head) * 32 + hd) * NTOK + nloc0) = pk;
                }
            }
        }
    }
}

// ---------------- kernel 2: fused window attention (swapped-S) ----------------
// grid 768 = 128 win x 6 heads, 256 threads (4 waves), 3 blocks/CU.
// S^T = mfma(K,Q): lane holds (ktok=g*4+j, qrow=l15) -> directly the A-frag of
// 16x16x16 PV mfma. Softmax is per-lane + 2 shfl_xor. No P transpose at all.
__global__ __launch_bounds__(256, 3) void attn_kernel(
    const f16* __restrict__ q_ws, const f16* __restrict__ k_ws,
    const f16* __restrict__ v_ws, const f16* __restrict__ rpb_h,
    const f16* __restrict__ mask_h, f16* __restrict__ o_ws)
{
    __shared__ __align__(16) f16 k_lds[25 * 512];   // frag-major, 25.6 KB
    __shared__ __align__(16) f16 v_lds[32 * 408];   // V^T rows padded, 26.1 KB

    const int tid = threadIdx.x;
    const int bid = blockIdx.x;
    const int win = bid / 6, head = bid - win * 6;
    const int wd = win >> 6, wh = (win >> 3) & 7, ww = win & 7;
    const int wtype = ((wd == 1) ? 4 : 0) | ((wh == 7) ? 2 : 0) | ((ww == 7) ? 1 : 0);
    const f16* kb = k_ws + (size_t)(win * HEADS + head) * NTOK * 32;
    const f16* vb = v_ws + (size_t)(win * HEADS + head) * 32 * NTOK;
    const f16* qb = q_ws + (size_t)(win * HEADS + head) * NTOK * 32;
    const f16* biasb = rpb_h + head * 160000;
    const f16* maskb = mask_h + wtype * 160000;

    // K frag-major: tile t, lane l -> K[t*16+(l&15)][(l>>4)*8..+8] at (t*64+l)*16B
    for (int i = tid; i < 1600; i += 256) {
        const int tok = ((i >> 6) << 4) | (i & 15);
        const int gg = (i >> 4) & 3;
        f16x8 v = f16x8_zero();
        if (tok < NTOK) v = *(const f16x8*)(kb + tok * 32 + gg * 8);
        *(f16x8*)&k_lds[i * 8] = v;
    }
    // V^T rows: v_lds[hd][tok], stride 408 (2-way bank alias = free)
    for (int i = tid; i < 32 * 51; i += 256) {
        const int hd = i / 51, c = i - hd * 51;
        f16x8 v = f16x8_zero();
        if (c < 49) v = *(const f16x8*)(vb + hd * NTOK + c * 8);
        *(f16x8*)&v_lds[hd * 408 + c * 8] = v;
    }
    __syncthreads();

    const int lane = tid & 63, wv = tid >> 6, l15 = lane & 15, g = lane >> 4;
    const f32x4 z4 = {0.f, 0.f, 0.f, 0.f};

    for (int strip = wv; strip < 25; strip += 4) {
        const int q0 = strip * 16;
        int qr = q0 + l15; if (qr > NTOK - 1) qr = NTOK - 1;
        const f16x8 qf = *(const f16x8*)(qb + qr * 32 + g * 8);  // B: qrow=l15

        // S^T tiles: A = K-tile (ktok=l15 rows), B = Q
        f32x4 acc[25];
        #pragma unroll
        for (int t = 0; t < 25; t++) {
            const f16x8 kf = *(const f16x8*)&k_lds[t * 512 + lane * 8];
            acc[t] = MFMA_K32(kf, qf, z4);
        }

        // + rpb + shift mask (f16x4 row-major, both pre-scaled by log2e)
        const int brow = q0 + l15;  // 0..399, valid table row
        const f16* bp = biasb + brow * 400;
        const f16* mp = maskb + brow * 400;
        #pragma unroll
        for (int t = 0; t < 25; t++) {
            const f16x4 b4 = *(const f16x4*)(bp + t * 16 + g * 4);
            const f16x4 m4 = *(const f16x4*)(mp + t * 16 + g * 4);
            #pragma unroll
            for (int j = 0; j < 4; j++)
                acc[t][j] += (float)b4[j] + (float)m4[j];
        }

        // softmax over ktok for row l15: in-lane over 100 vals + shfl_xor(16,32)
        float mx = acc[0][0];
        #pragma unroll
        for (int t = 0; t < 25; t++) {
            #pragma unroll
            for (int j = 0; j < 4; j++) mx = fmaxf(mx, acc[t][j]);
        }
        mx = fmaxf(mx, __shfl_xor(mx, 16));
        mx = fmaxf(mx, __shfl_xor(mx, 32));
        float s = 0.f;
        #pragma unroll
        for (int t = 0; t < 25; t++) {
            #pragma unroll
            for (int j = 0; j < 4; j++) {
                const float e = EXP2F(acc[t][j] - mx);
                acc[t][j] = e;
                s += e;
            }
        }
        s += __shfl_xor(s, 16);
        s += __shfl_xor(s, 32);
        const float rinv = 1.0f / s;   // for qrow = l15

        // O = P V via 16x16x16: P frag is acc directly (qrow=l15, ktok=g*4+j)
        f32x4 oacc[2] = {z4, z4};
        #pragma unroll
        for (int t = 0; t < 25; t++) {
            f16x4 pa;
            #pragma unroll
            for (int j = 0; j < 4; j++) pa[j] = (f16)acc[t][j];
            #pragma unroll
            for (int nt = 0; nt < 2; nt++) {
                const f16x4 vf = *(const f16x4*)&v_lds[(nt * 16 + l15) * 408 + t * 16 + g * 4];
                oacc[nt] = MFMA_K16(pa, vf, oacc[nt]);
            }
        }

        // output rows qrow = q0 + g*4 + j; fetch that row's 1/sum from lane g*4+j
        #pragma unroll
        for (int j = 0; j < 4; j++) {
            const float rj = __shfl(rinv, g * 4 + j);
            const int row = q0 + g * 4 + j;
            if (row < NTOK) {
                f16* dst = o_ws + ((size_t)win * NTOK + row) * CDIM + head * 32;
                dst[l15]      = (f16)(oacc[0][j] * rj);
                dst[16 + l15] = (f16)(oacc[1][j] * rj);
            }
        }
    }
}

// ---------------- kernel 3: proj GEMM + window-reverse/roll scatter ----------------
__global__ __launch_bounds__(256, 3) void proj_kernel(
    const f16* __restrict__ o_ws, const f16* __restrict__ wp,
    const float* __restrict__ bp, float* __restrict__ out)
{
    __shared__ __align__(16) f16 a_lds[64 * 256];
    const int tid = threadIdx.x;
    const int bm = blockIdx.x * 64;
    for (int i = tid; i < 64 * 24; i += 256) {
        int row = i / 24, c = i - row * 24;
        f16x8 v = *(const f16x8*)(o_ws + (size_t)(bm + row) * CDIM + c * 8);
        *(f16x8*)&a_lds[row * 256 + ((c ^ (row & 7)) << 3)] = v;
    }
    __syncthreads();

    const int lane = tid & 63, wv = tid >> 6;
    const int l15 = lane & 15, g = lane >> 4;
    const int m0 = (wv & 1) * 32, n0 = (wv >> 1) * 96;

    const f32x4 z4 = {0.f, 0.f, 0.f, 0.f};
    f32x4 acc[2][6];
    #pragma unroll
    for (int mi = 0; mi < 2; mi++)
        #pragma unroll
        for (int ni = 0; ni < 6; ni++) acc[mi][ni] = z4;

    #pragma unroll
    for (int kk = 0; kk < 6; kk++) {
        f16x8 af[2];
        #pragma unroll
        for (int mi = 0; mi < 2; mi++) {
            int row = m0 + mi * 16 + l15;
            af[mi] = *(const f16x8*)&a_lds[row * 256 + (((kk * 4 + g) ^ (row & 7)) << 3)];
        }
        #pragma unroll
        for (int ni = 0; ni < 6; ni++) {
            const f16x8 bf = *(const f16x8*)&wp[(n0 + ni * 16 + l15) * CDIM + kk * 32 + g * 8];
            #pragma unroll
            for (int mi = 0; mi < 2; mi++)
                acc[mi][ni] = MFMA_K32(af[mi], bf, acc[mi][ni]);
        }
    }

    #pragma unroll
    for (int mi = 0; mi < 2; mi++) {
        const int tok0 = bm + m0 + mi * 16 + g * 4;
        #pragma unroll
        for (int j = 0; j < 4; j++) {
            const int tok = tok0 + j;
            const int win = tok / NTOK, nloc = tok - win * NTOK;
            const int td = nloc / 49, r2 = nloc - td * 49, th = r2 / 7, tw = r2 - th * 7;
            const int wd = win >> 6, wh = (win >> 3) & 7, ww = win & 7;
            const int d = (wd * 8 + td + 4) & 15;
            int hh = wh * 7 + th + 3; if (hh >= 56) hh -= 56;
            int wco = ww * 7 + tw + 3; if (wco >= 56) wco -= 56;
            float* dst = out + ((d * 56 + hh) * 56 + wco) * CDIM;
            #pragma unroll
            for (int ni = 0; ni < 6; ni++) {
                const int n = n0 + ni * 16 + l15;
                dst[n] = acc[mi][ni][j] + bp[n];
            }
        }
    }
}

// ---------------- launch ----------------
extern "C" void kernel_launch(void* const* d_in, const int* in_sizes, int n_in,
                              void* d_out, int out_size, void* d_ws, size_t ws_size,
                              hipStream_t stream) {
    const float* x     = (const float*)d_in[0];
    const float* wqkv  = (const float*)d_in[1];
    const float* bqkv  = (const float*)d_in[2];
    const float* wproj = (const float*)d_in[3];
    const float* bproj = (const float*)d_in[4];
    const float* rtbl  = (const float*)d_in[5];
    float* out = (float*)d_out;

    // workspace layout (~81.9 MB)
    const size_t QKV_BYTES = (size_t)NWIN * HEADS * NTOK * 32 * sizeof(f16);  // 19,267,584
    char* ws = (char*)d_ws;
    f16* q_ws   = (f16*)(ws);
    f16* k_ws   = (f16*)(ws + QKV_BYTES);
    f16* v_ws   = (f16*)(ws + 2 * QKV_BYTES);
    f16* o_ws   = (f16*)(ws + 3 * QKV_BYTES);
    f16* rpb_h  = (f16*)(ws + 4 * QKV_BYTES);                       // 1,920,000 B
    f16* mask_h = (f16*)(ws + 4 * QKV_BYTES + 1920000);             // 2,560,000 B
    f16* wq_h   = (f16*)(ws + 4 * QKV_BYTES + 1920000 + 2560000);   // 221,184 B
    f16* wp_h   = (f16*)(ws + 4 * QKV_BYTES + 1920000 + 2560000 + 221184);

    wconv_kernel<<<432, 256, 0, stream>>>(wqkv, wproj, wq_h, wp_h);
    tab_kernel<<<5000, 256, 0, stream>>>(rtbl, rpb_h, mask_h);
    qkv_kernel<<<784, 256, 0, stream>>>(x, wq_h, bqkv, q_ws, k_ws, v_ws);
    attn_kernel<<<768, 256, 0, stream>>>(q_ws, k_ws, v_ws, rpb_h, mask_h, o_ws);
    proj_kernel<<<784, 256, 0, stream>>>(o_ws, wp_h, bproj, out);
}